// Round 1
// baseline (213.368 us; speedup 1.0000x reference)
//
#include <hip/hip_runtime.h>

#define NTHR 256
#define TB 64

typedef float4 f4;

__device__ __forceinline__ void fma4(f4& a, float s, const f4& b) {
  a.x = fmaf(s, b.x, a.x); a.y = fmaf(s, b.y, a.y);
  a.z = fmaf(s, b.z, a.z); a.w = fmaf(s, b.w, a.w);
}

__device__ __forceinline__ f4 zero4() { return make_float4(0.f, 0.f, 0.f, 0.f); }

// LDS layout (floats):
//   s_ch  [64][132] : ch[i][c*64 + a*16 + r]        (stride 132: bank-spread)
//   s_tp  [64][36]  : tp[i][a*8 + p]                (stride 36)
//   s_g   [64][80]  : g[i][a*20 + s]                (stride 80)
//   s_big [20736]   : scratch union: te+Ut | nh-chunk[64][132] | O[64][324] |
//                     gred[16][64][16] | U_output[4][16][256]
// total = (8448 + 2304 + 5120 + 20736) * 4 = 146432 B < 160 KiB

extern "C" __global__ __launch_bounds__(NTHR, 1)
void hosvd_fused(const float* __restrict__ nh,  // (BS,2,256)
                 const float* __restrict__ te,  // (BS,32)
                 const float* __restrict__ Uw,  // (2,4,256,16)
                 const float* __restrict__ bw,  // (2,4,1,16)
                 const float* __restrict__ Ut,  // (32,32)
                 const float* __restrict__ bt,  // (1,32)
                 const float* __restrict__ Tw,  // (4,9,17,17,16)
                 const float* __restrict__ UO,  // (4,16,256)
                 const float* __restrict__ bO,  // (4,1,256)
                 float* __restrict__ out)       // (BS,1024)
{
  __shared__ __align__(16) float s_ch[TB * 132];
  __shared__ __align__(16) float s_tp[TB * 36];
  __shared__ __align__(16) float s_g [TB * 80];
  __shared__ __align__(16) float s_big[20736];

  const int t = threadIdx.x;
  const int ib0 = blockIdx.x * TB;

  //======== Phase B: tp = te @ Ut + bt -> s_tp ========
  {
    float* te_l = s_big;            // [64][33]
    float* Ut_l = s_big + TB * 33;  // [32][32]
    for (int l = t; l < TB * 8; l += NTHR) {        // 512 float4 of te
      int i = l >> 3, c4 = (l & 7) * 4;
      f4 v = *(const f4*)&te[(size_t)(ib0 + i) * 32 + c4];
      te_l[i * 33 + c4 + 0] = v.x;
      te_l[i * 33 + c4 + 1] = v.y;
      te_l[i * 33 + c4 + 2] = v.z;
      te_l[i * 33 + c4 + 3] = v.w;
    }
    {
      int l = t;
      if (l < 256) *(f4*)&Ut_l[l * 4] = *(const f4*)&Ut[l * 4];
    }
    __syncthreads();
    const int i = t >> 2, a = t & 3;
    float acc[8];
    #pragma unroll
    for (int j = 0; j < 8; ++j) acc[j] = bt[a * 8 + j];
    for (int k = 0; k < 32; ++k) {
      float tv = te_l[i * 33 + k];
      #pragma unroll
      for (int j = 0; j < 8; ++j) acc[j] = fmaf(tv, Ut_l[k * 32 + a * 8 + j], acc[j]);
    }
    #pragma unroll
    for (int j = 0; j < 8; ++j) s_tp[i * 36 + a * 8 + j] = acc[j];
  }
  __syncthreads();

  //======== Phase C: ch[i][c][a][r] = nh[i][c] @ U[c] + b  -> s_ch ========
  {
    const int ig = t & 15, cg = t >> 4;          // items ig+16*ii, cols cg*4+cc
    const int ca = cg >> 2, r0 = (cg & 3) * 4;   // col -> (a, r0)
    for (int c = 0; c < 2; ++c) {
      f4 acc[4];
      #pragma unroll
      for (int ii = 0; ii < 4; ++ii) acc[ii] = zero4();
      for (int hb = 0; hb < 2; ++hb) {
        __syncthreads();
        for (int l = t; l < 2048; l += NTHR) {   // stage nh chunk [64][128]
          int i = l >> 5, c4 = (l & 31) * 4;
          *(f4*)&s_big[i * 132 + c4] =
              *(const f4*)&nh[((size_t)(ib0 + i) * 2 + c) * 256 + hb * 128 + c4];
        }
        __syncthreads();
        const float* Ub = Uw + ((size_t)(c * 4 + ca) * 256 + hb * 128) * 16 + r0;
        for (int k0 = 0; k0 < 128; k0 += 4) {
          f4 av[4], bv[4];
          #pragma unroll
          for (int ii = 0; ii < 4; ++ii)
            av[ii] = *(const f4*)&s_big[(ig + 16 * ii) * 132 + k0];
          #pragma unroll
          for (int j2 = 0; j2 < 4; ++j2)
            bv[j2] = *(const f4*)&Ub[(k0 + j2) * 16];
          #pragma unroll
          for (int ii = 0; ii < 4; ++ii) {
            fma4(acc[ii], av[ii].x, bv[0]);
            fma4(acc[ii], av[ii].y, bv[1]);
            fma4(acc[ii], av[ii].z, bv[2]);
            fma4(acc[ii], av[ii].w, bv[3]);
          }
        }
      }
      f4 bias = *(const f4*)&bw[(c * 4 + ca) * 16 + r0];
      #pragma unroll
      for (int ii = 0; ii < 4; ++ii) {
        f4 w = acc[ii];
        w.x += bias.x; w.y += bias.y; w.z += bias.z; w.w += bias.w;
        *(f4*)&s_ch[(ig + 16 * ii) * 132 + c * 64 + cg * 4] = w;
      }
    }
  }
  __syncthreads();

  //======== Phase D: core contraction ========
  // thread decomposition: 8 item-groups x 2 s-groups x 16 k-slices
  const int ig2 = t & 7;          // items ig2 + 8*ii
  const int sg  = (t >> 3) & 1;   // s = sg*8 + ss
  const int ksl = t >> 4;         // 16 k-slices over 292 (pad of 289)
  const int kstart = (ksl < 9) ? ksl * 20 : 180 + (ksl - 9) * 16;
  const int klen   = (ksl < 9) ? 20 : 16;

  for (int a = 0; a < 4; ++a) {
    // build O[i][k] = h1[q]*h2[r] (qr = q*17+r), zero pad k=289..291; stride 324
    for (int l = t; l < 64 * 292; l += NTHR) {
      int k = l >> 6;       // wave-uniform
      int i = l & 63;
      float v = 0.f;
      if (k < 289) {
        unsigned q = (unsigned)k / 17u, r = (unsigned)k % 17u;
        float h1 = (q < 16u) ? s_ch[i * 132 + a * 16 + (int)q] : 1.f;
        float h2 = (r < 16u) ? s_ch[i * 132 + 64 + a * 16 + (int)r] : 1.f;
        v = h1 * h2;
      }
      s_big[i * 324 + k] = v;
    }
    __syncthreads();

    f4 gg0[8], gg1[8];
    #pragma unroll
    for (int ii = 0; ii < 8; ++ii) { gg0[ii] = zero4(); gg1[ii] = zero4(); }

    for (int p = 0; p < 9; ++p) {
      const float* Tp = Tw + (size_t)(a * 9 + p) * 4624 + sg * 8;
      float h0v[8];
      #pragma unroll
      for (int ii = 0; ii < 8; ++ii)
        h0v[ii] = (p < 8) ? s_tp[(ig2 + 8 * ii) * 36 + a * 8 + p] : 1.f;

      f4 pa0[8], pa1[8];
      #pragma unroll
      for (int ii = 0; ii < 8; ++ii) { pa0[ii] = zero4(); pa1[ii] = zero4(); }

      for (int j = 0; j < klen; j += 4) {
        const int k0 = kstart + j;
        f4 ov[8];
        #pragma unroll
        for (int ii = 0; ii < 8; ++ii)
          ov[ii] = *(const f4*)&s_big[(ig2 + 8 * ii) * 324 + k0];
        // clamp T row index to <=288 (rows 289..291 multiply O==0, value irrelevant)
        int kk1 = k0 + 1; if (kk1 > 288) kk1 = 288;
        int kk2 = k0 + 2; if (kk2 > 288) kk2 = 288;
        int kk3 = k0 + 3; if (kk3 > 288) kk3 = 288;
        f4 t0a = *(const f4*)&Tp[k0 * 16],  t0b = *(const f4*)&Tp[k0 * 16 + 4];
        f4 t1a = *(const f4*)&Tp[kk1 * 16], t1b = *(const f4*)&Tp[kk1 * 16 + 4];
        f4 t2a = *(const f4*)&Tp[kk2 * 16], t2b = *(const f4*)&Tp[kk2 * 16 + 4];
        f4 t3a = *(const f4*)&Tp[kk3 * 16], t3b = *(const f4*)&Tp[kk3 * 16 + 4];
        #pragma unroll
        for (int ii = 0; ii < 8; ++ii) {
          fma4(pa0[ii], ov[ii].x, t0a); fma4(pa1[ii], ov[ii].x, t0b);
          fma4(pa0[ii], ov[ii].y, t1a); fma4(pa1[ii], ov[ii].y, t1b);
          fma4(pa0[ii], ov[ii].z, t2a); fma4(pa1[ii], ov[ii].z, t2b);
          fma4(pa0[ii], ov[ii].w, t3a); fma4(pa1[ii], ov[ii].w, t3b);
        }
      }
      #pragma unroll
      for (int ii = 0; ii < 8; ++ii) {
        fma4(gg0[ii], h0v[ii], pa0[ii]);
        fma4(gg1[ii], h0v[ii], pa1[ii]);
      }
    }
    __syncthreads();   // all O reads done; reuse s_big as gred[16][64][16]

    #pragma unroll
    for (int ii = 0; ii < 8; ++ii) {
      *(f4*)&s_big[ksl * 1024 + (ig2 + 8 * ii) * 16 + sg * 8 + 0] = gg0[ii];
      *(f4*)&s_big[ksl * 1024 + (ig2 + 8 * ii) * 16 + sg * 8 + 4] = gg1[ii];
    }
    __syncthreads();

    {  // reduce 16 k-partials -> s_g
      const int i = t >> 2, s4 = (t & 3) * 4;
      f4 r = zero4();
      #pragma unroll
      for (int kk = 0; kk < 16; ++kk) {
        f4 v = *(const f4*)&s_big[kk * 1024 + i * 16 + s4];
        r.x += v.x; r.y += v.y; r.z += v.z; r.w += v.w;
      }
      *(f4*)&s_g[i * 80 + a * 20 + s4] = r;
    }
    __syncthreads();   // before next-a O build overwrites gred
  }

  //======== Phase E: out = g @ U_output + b_output ========
  for (int l = t; l < 4096; l += NTHR)      // stage UO [4][16][256] = 64KB
    *(f4*)&s_big[l * 4] = *(const f4*)&UO[l * 4];
  __syncthreads();
  {
    const int i2  = (t >> 3) * 2;   // two items: i2, i2+1
    const int cg8 = t & 7;
    for (int a = 0; a < 4; ++a) {
      float g0[16], g1[16];
      #pragma unroll
      for (int s4 = 0; s4 < 16; s4 += 4) {
        *(f4*)&g0[s4] = *(const f4*)&s_g[(i2 + 0) * 80 + a * 20 + s4];
        *(f4*)&g1[s4] = *(const f4*)&s_g[(i2 + 1) * 80 + a * 20 + s4];
      }
      for (int j = 0; j < 8; ++j) {
        const int h = j * 32 + cg8 * 4;
        f4 b4 = *(const f4*)&bO[a * 256 + h];
        f4 acc0 = b4, acc1 = b4;
        #pragma unroll
        for (int s = 0; s < 16; ++s) {
          f4 u = *(const f4*)&s_big[(a * 16 + s) * 256 + h];
          fma4(acc0, g0[s], u);
          fma4(acc1, g1[s], u);
        }
        *(f4*)&out[(size_t)(ib0 + i2 + 0) * 1024 + a * 256 + h] = acc0;
        *(f4*)&out[(size_t)(ib0 + i2 + 1) * 1024 + a * 256 + h] = acc1;
      }
    }
  }
}

extern "C" void kernel_launch(void* const* d_in, const int* in_sizes, int n_in,
                              void* d_out, int out_size, void* d_ws, size_t ws_size,
                              hipStream_t stream) {
  const float* nh = (const float*)d_in[0];
  const float* te = (const float*)d_in[1];
  const float* Uw = (const float*)d_in[2];
  const float* bw = (const float*)d_in[3];
  const float* Ut = (const float*)d_in[4];
  const float* bt = (const float*)d_in[5];
  const float* Tw = (const float*)d_in[6];
  const float* UO = (const float*)d_in[7];
  const float* bO = (const float*)d_in[8];
  float* out = (float*)d_out;

  const int bs   = in_sizes[0] / 512;   // (BS, 2, 256)
  const int grid = bs / TB;             // 16384/64 = 256 workgroups

  hipLaunchKernelGGL(hosvd_fused, dim3(grid), dim3(NTHR), 0, stream,
                     nh, te, Uw, bw, Ut, bt, Tw, UO, bO, out);
}

// Round 2
// 103.161 us; speedup vs baseline: 2.0683x; 2.0683x over previous
//
#include <hip/hip_runtime.h>

#define NTHR 512
#define TB 64

typedef __attribute__((ext_vector_type(8))) short bf16x8;
typedef __attribute__((ext_vector_type(4))) float f32x4;
typedef float4 f4;
typedef unsigned short u16;

__device__ __forceinline__ u16 f2b(float x) {
  union { float f; unsigned u; } v; v.f = x;
  unsigned r = (v.u + 0x7fffu + ((v.u >> 16) & 1u)) >> 16;
  return (u16)r;
}
__device__ __forceinline__ float b2f(u16 u) {
  union { unsigned u; float f; } v; v.u = ((unsigned)u) << 16;
  return v.f;
}
__device__ __forceinline__ unsigned pack2(float a, float b) {
  return (unsigned)f2b(a) | ((unsigned)f2b(b) << 16);
}

// ---------------- prep: k-major bf16 weight copies in ws ----------------
// BT [a][n=144][kk=320]  : T[a,p,q,r,s], n=p*16+s, kk=q*17+r (pad>=289 -> 0)
// UcT[c][n=64][k=256]    : U[c,a,k,r],   n=a*16+r
// UOT[a][h=256][kk=32]   : UO[a,s,h] transposed, kk=s (pad>=16 -> 0)
extern "C" __global__ void hosvd_prep(const float* __restrict__ U,
                                      const float* __restrict__ T,
                                      const float* __restrict__ UO,
                                      unsigned* __restrict__ ws32) {
  int id = blockIdx.x * 256 + threadIdx.x;
  if (id < 92160) {                       // BT: 4*144*160 u32
    int a = id / 23040, rem = id % 23040;
    int n = rem / 160, sl = rem % 160;
    int p = n >> 4, s = n & 15;
    int kk0 = sl * 2;
    float v[2];
    #pragma unroll
    for (int j = 0; j < 2; ++j) {
      int kk = kk0 + j;
      float x = 0.f;
      if (kk < 289) {
        int qq = (unsigned)kk / 17u, rr = kk - qq * 17;
        x = T[(((a * 9 + p) * 17 + qq) * 17 + rr) * 16 + s];
      }
      v[j] = x;
    }
    ws32[id] = pack2(v[0], v[1]);
  } else if (id < 108544) {               // UcT: 2*64*128 u32
    int rel = id - 92160;
    int c = rel / 8192, n = (rel / 128) & 63, kp = rel & 127;
    int a = n >> 4, r = n & 15, k0 = kp * 2;
    float v0 = U[((c * 4 + a) * 256 + k0 + 0) * 16 + r];
    float v1 = U[((c * 4 + a) * 256 + k0 + 1) * 16 + r];
    ws32[id] = pack2(v0, v1);
  } else if (id < 124928) {               // UOT: 4*256*16 u32
    int rel = id - 108544;
    int a = rel / 4096, h = (rel / 16) & 255, kp = rel & 15;
    int k0 = kp * 2;
    float v0 = (k0 + 0 < 16) ? UO[(a * 16 + k0 + 0) * 256 + h] : 0.f;
    float v1 = (k0 + 1 < 16) ? UO[(a * 16 + k0 + 1) * 256 + h] : 0.f;
    ws32[id] = pack2(v0, v1);
  }
}

// ---------------- main fused kernel ----------------
// LDS: s_u 81920 B (union: nh bf16 [64][2][320] swz | O bf16 [64][2][320] swz)
//      s_ch bf16 [64][132], s_tp f32 [64][36], s_g bf16 [64][136]
extern "C" __global__ __launch_bounds__(NTHR, 2)
void hosvd_main(const float* __restrict__ nh, const float* __restrict__ te,
                const float* __restrict__ bw, const float* __restrict__ Ut,
                const float* __restrict__ bt, const float* __restrict__ bO,
                const u16* __restrict__ BT, const u16* __restrict__ UcT,
                const u16* __restrict__ UOT, float* __restrict__ out) {
  __shared__ __align__(16) u16   s_u[40960];
  __shared__ __align__(16) u16   s_ch[TB * 132];
  __shared__ __align__(16) float s_tp[TB * 36];
  __shared__ __align__(16) u16   s_g[TB * 136];

  const int t = threadIdx.x;
  const int ib0 = blockIdx.x * TB;
  const int w = t >> 6, l = t & 63;
  const int rl = l & 15, q = l >> 4;
  const int m = w >> 1, par = w & 1;   // wave = (mtile, parity)
  const int row7 = rl & 7;

  //---- Phase B: tp = te @ Ut + bt -> s_tp (f32) ----
  {
    const int i = t >> 3, a = (t >> 1) & 3, jh = t & 1;
    float acc[4];
    #pragma unroll
    for (int jj = 0; jj < 4; ++jj) acc[jj] = bt[a * 8 + jh * 4 + jj];
    for (int k = 0; k < 32; ++k) {
      float tv = te[(size_t)(ib0 + i) * 32 + k];
      #pragma unroll
      for (int jj = 0; jj < 4; ++jj)
        acc[jj] = fmaf(tv, Ut[k * 32 + a * 8 + jh * 4 + jj], acc[jj]);
    }
    #pragma unroll
    for (int jj = 0; jj < 4; ++jj) s_tp[i * 36 + a * 8 + jh * 4 + jj] = acc[jj];
  }

  //---- Phase C stage: nh (both children) -> s_u bf16, XOR-swizzled ----
  for (int lp = t; lp < 8192; lp += NTHR) {
    int rowi = lp >> 7, cc = (lp >> 6) & 1, ck = lp & 63;
    f4 v = *(const f4*)&nh[((size_t)(ib0 + rowi) * 2 + cc) * 256 + ck * 4];
    int k0 = ck * 4;
    int idx = rowi * 640 + (((cc * 40 + (k0 >> 3)) ^ (rowi & 7)) << 3) + (k0 & 7);
    *(uint2*)&s_u[idx] = make_uint2(pack2(v.x, v.y), pack2(v.z, v.w));
  }
  __syncthreads();

  //---- Phase C GEMM: ch = nh @ U + bw -> s_ch bf16 ----
  for (int c = 0; c < 2; ++c) {
    f32x4 acc0 = {0.f, 0.f, 0.f, 0.f}, acc1 = {0.f, 0.f, 0.f, 0.f};
    const int n0 = (par * 2 + 0) * 16 + rl, n1 = (par * 2 + 1) * 16 + rl;
    #pragma unroll
    for (int kt = 0; kt < 8; ++kt) {
      int ak = kt * 32 + 8 * q;
      int aidx = (m * 16 + rl) * 640 + (((c * 40 + (ak >> 3)) ^ row7) << 3);
      bf16x8 A  = *(const bf16x8*)&s_u[aidx];
      bf16x8 B0 = *(const bf16x8*)&UcT[(c * 64 + n0) * 256 + ak];
      bf16x8 B1 = *(const bf16x8*)&UcT[(c * 64 + n1) * 256 + ak];
      acc0 = __builtin_amdgcn_mfma_f32_16x16x32_bf16(A, B0, acc0, 0, 0, 0);
      acc1 = __builtin_amdgcn_mfma_f32_16x16x32_bf16(A, B1, acc1, 0, 0, 0);
    }
    float bias0 = bw[c * 64 + n0], bias1 = bw[c * 64 + n1];
    #pragma unroll
    for (int reg = 0; reg < 4; ++reg) {
      int rowi = m * 16 + 4 * q + reg;
      s_ch[rowi * 132 + c * 64 + n0] = f2b(acc0[reg] + bias0);
      s_ch[rowi * 132 + c * 64 + n1] = f2b(acc1[reg] + bias1);
    }
  }
  __syncthreads();

  //---- Core: per a-pair {aB, aB+1}: build O tile, GEMM vs BT, h0-epilogue ----
  for (int aB = 0; aB < 4; aB += 2) {
    for (int lp = t; lp < 10240; lp += NTHR) {      // O[row][aL][k<320] bf16
      unsigned rowi = (unsigned)lp / 160u;
      int quad = lp - (int)rowi * 160;
      int aL = quad >= 80;
      int k0 = (quad - aL * 80) * 4;
      int a = aB + aL;
      float vv[4];
      #pragma unroll
      for (int j = 0; j < 4; ++j) {
        int kk = k0 + j;
        float x = 0.f;
        if (kk < 289) {
          unsigned qq = (unsigned)kk / 17u;
          unsigned rr = (unsigned)kk - qq * 17u;
          float h1 = (qq < 16u) ? b2f(s_ch[rowi * 132 + a * 16 + qq]) : 1.f;
          float h2 = (rr < 16u) ? b2f(s_ch[rowi * 132 + 64 + a * 16 + rr]) : 1.f;
          x = h1 * h2;
        }
        vv[j] = x;
      }
      int idx = rowi * 640 + (((aL * 40 + (k0 >> 3)) ^ ((int)rowi & 7)) << 3) + (k0 & 7);
      *(uint2*)&s_u[idx] = make_uint2(pack2(vv[0], vv[1]), pack2(vv[2], vv[3]));
    }
    __syncthreads();

    {
      const int a = aB + par;
      f32x4 acc[9];
      #pragma unroll
      for (int p = 0; p < 9; ++p) acc[p] = (f32x4){0.f, 0.f, 0.f, 0.f};
      for (int kt = 0; kt < 10; ++kt) {
        int ak = kt * 32 + 8 * q;
        int aidx = (m * 16 + rl) * 640 + (((par * 40 + (ak >> 3)) ^ row7) << 3);
        bf16x8 A = *(const bf16x8*)&s_u[aidx];
        #pragma unroll
        for (int p = 0; p < 9; ++p) {
          bf16x8 B = *(const bf16x8*)&BT[(a * 144 + p * 16 + rl) * 320 + ak];
          acc[p] = __builtin_amdgcn_mfma_f32_16x16x32_bf16(A, B, acc[p], 0, 0, 0);
        }
      }
      #pragma unroll
      for (int reg = 0; reg < 4; ++reg) {
        int rowi = m * 16 + 4 * q + reg;
        f4 ha = *(const f4*)&s_tp[rowi * 36 + a * 8];
        f4 hb = *(const f4*)&s_tp[rowi * 36 + a * 8 + 4];
        float g = acc[8][reg];
        g = fmaf(ha.x, acc[0][reg], g);
        g = fmaf(ha.y, acc[1][reg], g);
        g = fmaf(ha.z, acc[2][reg], g);
        g = fmaf(ha.w, acc[3][reg], g);
        g = fmaf(hb.x, acc[4][reg], g);
        g = fmaf(hb.y, acc[5][reg], g);
        g = fmaf(hb.z, acc[6][reg], g);
        g = fmaf(hb.w, acc[7][reg], g);
        s_g[rowi * 136 + a * 32 + rl]      = f2b(g);
        s_g[rowi * 136 + a * 32 + 16 + rl] = 0;   // zero K-pad for phase E
      }
    }
    __syncthreads();
  }

  //---- Phase E: out = g @ U_output + b_output (MFMA, K=16 padded to 32) ----
  #pragma unroll
  for (int a = 0; a < 4; ++a) {
    bf16x8 A = *(const bf16x8*)&s_g[(m * 16 + rl) * 136 + a * 32 + 8 * q];
    #pragma unroll
    for (int nt = 0; nt < 8; ++nt) {
      int h = (par * 8 + nt) * 16 + rl;
      bf16x8 B = *(const bf16x8*)&UOT[(a * 256 + h) * 32 + 8 * q];
      float bias = bO[a * 256 + h];
      f32x4 accE = {bias, bias, bias, bias};
      accE = __builtin_amdgcn_mfma_f32_16x16x32_bf16(A, B, accE, 0, 0, 0);
      #pragma unroll
      for (int reg = 0; reg < 4; ++reg)
        out[(size_t)(ib0 + m * 16 + 4 * q + reg) * 1024 + a * 256 + h] = accE[reg];
    }
  }
}

extern "C" void kernel_launch(void* const* d_in, const int* in_sizes, int n_in,
                              void* d_out, int out_size, void* d_ws, size_t ws_size,
                              hipStream_t stream) {
  const float* nh = (const float*)d_in[0];
  const float* te = (const float*)d_in[1];
  const float* U  = (const float*)d_in[2];
  const float* bw = (const float*)d_in[3];
  const float* Ut = (const float*)d_in[4];
  const float* bt = (const float*)d_in[5];
  const float* T  = (const float*)d_in[6];
  const float* UO = (const float*)d_in[7];
  const float* bO = (const float*)d_in[8];
  float* out = (float*)d_out;

  unsigned* ws32 = (unsigned*)d_ws;
  hipLaunchKernelGGL(hosvd_prep, dim3(488), dim3(256), 0, stream, U, T, UO, ws32);

  const u16* BT  = (const u16*)d_ws;          // 184320 elems
  const u16* UcT = BT + 184320;               // 32768 elems
  const u16* UOT = UcT + 32768;               // 32768 elems

  const int bs = in_sizes[0] / 512;           // (BS,2,256)
  hipLaunchKernelGGL(hosvd_main, dim3(bs / TB), dim3(NTHR), 0, stream,
                     nh, te, bw, Ut, bt, bO, BT, UcT, UOT, out);
}